// Round 10
// baseline (573.306 us; speedup 1.0000x reference)
//
#include <hip/hip_runtime.h>
#include <hip/hip_cooperative_groups.h>

// Deformable-DETR MSDeformAttn, Q=19947, D=256, M=8, L=4, P=4, DH=32.
// ROUND 10: cooperative single-dispatch fusion (r9 intent) made FAIL-SAFE.
// r9's coop launch silently failed (unchecked error -> no work -> absmax ==
// max|ref|). Now: grid sized from the runtime's occupancy query, launch
// return code checked, and on ANY failure the same call falls back to the
// proven r5 4-dispatch path. Fused phases and fallback kernels execute
// identical arithmetic in identical order -> bitwise-equal outputs, so the
// launch-once-vs-graph tripwire holds regardless of which path runs.

namespace cg = cooperative_groups;

#define DMODEL 256

typedef __attribute__((ext_vector_type(8))) short u16x8;      // raw 16-bit staging
typedef __attribute__((ext_vector_type(8))) _Float16 f16x8;   // MFMA A/B fragment
typedef __attribute__((ext_vector_type(4))) float f32x4;

static __device__ inline unsigned short f2h(float f) {
    return __builtin_bit_cast(unsigned short, (_Float16)f);   // v_cvt_f16_f32 (RNE)
}
static __device__ inline float h2f(unsigned short h) {
    return (float)__builtin_bit_cast(_Float16, h);
}
static __device__ inline float fast_rcp(float x) {
#if __has_builtin(__builtin_amdgcn_rcpf)
    return __builtin_amdgcn_rcpf(x);
#else
    return 1.f / x;
#endif
}
// DPP cross-lane move within 16-lane rows (VALU). row_ror:n ctrl = 0x120|n.
template<int CTRL>
static __device__ inline float dpp_mov_f32(float x) {
    return __builtin_bit_cast(float,
        __builtin_amdgcn_mov_dpp(__builtin_bit_cast(int, x), CTRL, 0xf, 0xf, false));
}
// Butterfly add across lane^16 / lane^32 via v_permlane*_swap (VALU, no DS).
static __device__ inline float bfly_add16(float x) {
    float a = x, b = x;
    asm("v_permlane16_swap_b32 %0, %1" : "+v"(a), "+v"(b));
    return a + b;
}
static __device__ inline float bfly_add32(float x) {
    float a = x, b = x;
    asm("v_permlane32_swap_b32 %0, %1" : "+v"(a), "+v"(b));
    return a + b;
}

struct Params {
    const float* query; const float* refpt; const float* inflat;
    const unsigned char* mask;
    const float* W_off; const float* b_off;
    const float* W_attn; const float* b_attn;
    const float* W_val; const float* b_val;
    const float* W_out; const float* b_out;
    float* out;
    unsigned short* value_h; float* offo; unsigned short* logits_h;
    unsigned short* out2;
    unsigned short* inflat_h; unsigned short* query_h;
    unsigned short* WtVal; unsigned short* WtOff;
    unsigned short* WtAttn; unsigned short* WtOut;
    int Q, QD, rb, na, nqb;
};

// ===========================================================================
// fused_k: all four phases in one cooperative dispatch, grid-stride loops.
// gridDim.x is a multiple of 8 (host guarantees) so m = vb&7 stays XCD-pinned.
// ===========================================================================
__global__ __launch_bounds__(256, 4) void fused_k(Params p)
{
    // LDS union across phases: gemm_in needs the max, 9216 + 18432 = 27648 B.
    __shared__ __align__(16) unsigned char smem[27648];
    cg::grid_group grid = cg::this_grid();
    const int t = threadIdx.x;
    const int Q = p.Q;
    const int NB = (int)gridDim.x;

    // ===================== phase 1: prep =====================
    {
        const int nvb = 56 + p.na;
        for (int vb = blockIdx.x; vb < nvb; vb += NB) {
            if (vb >= 56) {
                // A conversion: 8 consecutive floats per thread.
                const int f = ((vb - 56) * 256 + t) * 8;
                if (f < 2 * p.QD) {
                    const float* src; unsigned short* dst; int i;
                    if (f < p.QD) { src = p.inflat; dst = p.inflat_h; i = f; }
                    else          { src = p.query;  dst = p.query_h;  i = f - p.QD; }
                    const float4 v0 = *(const float4*)(src + i);
                    const float4 v1 = *(const float4*)(src + i + 4);
                    u16x8 h;
                    h[0] = (short)f2h(v0.x); h[1] = (short)f2h(v0.y);
                    h[2] = (short)f2h(v0.z); h[3] = (short)f2h(v0.w);
                    h[4] = (short)f2h(v1.x); h[5] = (short)f2h(v1.y);
                    h[6] = (short)f2h(v1.z); h[7] = (short)f2h(v1.w);
                    *(u16x8*)(dst + i) = h;
                }
            } else {
                // weight transpose: W[k][c] f32 -> Wt[c][k] fp16
                unsigned short (*tH)[68] = (unsigned short (*)[68])smem;
                int b = vb;
                const float* W; unsigned short* H; int NC;
                if (b < 16)      { W = p.W_val;  H = p.WtVal;  NC = 256; }
                else if (b < 32) { W = p.W_off;  H = p.WtOff;  NC = 256; b -= 16; }
                else if (b < 40) { W = p.W_attn; H = p.WtAttn; NC = 128; b -= 32; }
                else             { W = p.W_out;  H = p.WtOut;  NC = 256; b -= 40; }
                const int k0 = (b & 3) * 64, c0 = (b >> 2) * 64;
                const int cl = t & 63;
#pragma unroll
                for (int i = 0; i < 16; ++i) {
                    const int kl = (t >> 6) * 16 + i;
                    tH[cl][kl] = f2h(W[(size_t)(k0 + kl) * NC + c0 + cl]);
                }
                __syncthreads();
                const int kl = t & 63;
#pragma unroll
                for (int i = 0; i < 16; ++i) {
                    const int cl2 = (t >> 6) * 16 + i;
                    H[(size_t)(c0 + cl2) * 256 + k0 + kl] = tH[cl2][kl];
                }
                __syncthreads();   // guard LDS reuse on next virtual block
            }
        }
    }
    __threadfence();   // device-scope release: cross-XCD visibility (G16)
    grid.sync();

    // ===================== phase 2: gemm_in =====================
    {
        unsigned short (*As)[72] = (unsigned short (*)[72])smem;           // [64][72]
        unsigned short (*Bs)[72] = (unsigned short (*)[72])(smem + 9216);  // [128][72]
        const int w = t >> 6, lane = t & 63;
        const int lr = lane & 15, quad = lane >> 4;
        const int rwl = (w & 1) * 32, cwl = (w >> 1) * 64;
        const int a_r = t >> 2, a_q = (t & 3) * 16;   // A: row, 16-short k-span
        const int b_c = t >> 1, b_k = (t & 1) * 32;   // B: col, 32-short k-span
        const int nvb = p.rb * 5;

        for (int vb = blockIdx.x; vb < nvb; vb += NB) {
            const int y = vb / p.rb;
            const int r0 = (vb - y * p.rb) * 64;

            const unsigned short* A; const unsigned short* Bt; const float* bias; int c0;
            if (y < 2)      { A = p.inflat_h; Bt = p.WtVal;  bias = p.b_val;  c0 = y * 128; }
            else if (y < 4) { A = p.query_h;  Bt = p.WtOff;  bias = p.b_off;  c0 = (y - 2) * 128; }
            else            { A = p.query_h;  Bt = p.WtAttn; bias = p.b_attn; c0 = 0; }

            int ar = r0 + a_r; if (ar >= Q) ar = Q - 1;
            const unsigned short* Arow = A + (size_t)ar * 256;
            const unsigned short* Brow = Bt + (size_t)(c0 + b_c) * 256;

            f32x4 acc[2][4];
#pragma unroll
            for (int i = 0; i < 2; ++i)
#pragma unroll
                for (int j = 0; j < 4; ++j) acc[i][j] = (f32x4){0.f, 0.f, 0.f, 0.f};

            u16x8 av[2], bv[4];
            auto load_chunk = [&](int kc) {
#pragma unroll
                for (int j = 0; j < 2; ++j) av[j] = *(const u16x8*)(Arow + kc + a_q + j * 8);
#pragma unroll
                for (int j = 0; j < 4; ++j) bv[j] = *(const u16x8*)(Brow + kc + b_k + j * 8);
            };
            auto stage_store = [&]() {
#pragma unroll
                for (int j = 0; j < 2; ++j) *(u16x8*)&As[a_r][a_q + j * 8] = av[j];
#pragma unroll
                for (int j = 0; j < 4; ++j) *(u16x8*)&Bs[b_c][b_k + j * 8] = bv[j];
            };

            load_chunk(0);
            stage_store();
            __syncthreads();

#pragma unroll
            for (int ch = 0; ch < 4; ++ch) {
                if (ch < 3) load_chunk((ch + 1) * 64);   // in flight during MFMA
#pragma unroll
                for (int ks = 0; ks < 2; ++ks) {
                    const int kb = ks * 32 + quad * 8;
                    f16x8 af[2], bfr[4];
#pragma unroll
                    for (int rt = 0; rt < 2; ++rt)
                        af[rt] = *(const f16x8*)&As[rwl + rt * 16 + lr][kb];
#pragma unroll
                    for (int ct = 0; ct < 4; ++ct)
                        bfr[ct] = *(const f16x8*)&Bs[cwl + ct * 16 + lr][kb];
#pragma unroll
                    for (int rt = 0; rt < 2; ++rt)
#pragma unroll
                        for (int ct = 0; ct < 4; ++ct)
                            acc[rt][ct] = __builtin_amdgcn_mfma_f32_16x16x32_f16(
                                af[rt], bfr[ct], acc[rt][ct], 0, 0, 0);
                }
                if (ch < 3) { __syncthreads(); stage_store(); __syncthreads(); }
            }

            // epilogue: C/D layout col=lane&15, row=quad*4+reg
#pragma unroll
            for (int ct = 0; ct < 4; ++ct) {
                const int col = c0 + cwl + ct * 16 + lr;
                const float bb = bias[col];
#pragma unroll
                for (int rt = 0; rt < 2; ++rt)
#pragma unroll
                    for (int reg = 0; reg < 4; ++reg) {
                        const int r = r0 + rwl + rt * 16 + quad * 4 + reg;
                        if (r < Q) {
                            float v = acc[rt][ct][reg] + bb;
                            if (y < 2) {
                                if (p.mask && p.mask[r]) v = 0.f;
                                p.value_h[((size_t)(col >> 5) * Q + r) * 32 + (col & 31)] = f2h(v);
                            } else if (y < 4) {
                                p.offo[(size_t)r * 256 + col] = v;
                            } else {
                                p.logits_h[(size_t)r * 128 + col] = f2h(v * 1.44269504f);
                            }
                        }
                    }
            }
            __syncthreads();   // guard LDS reuse on next virtual block
        }
    }
    __threadfence();
    grid.sync();

    // ===================== phase 3: msda =====================
    {
        unsigned (*pkbuf)[256] = (unsigned (*)[256])smem;   // [4 waves][256]
        const int w = t >> 6;
        const int lane = t & 63;
        const int s = lane >> 4;             // q-slot 0..3
        const int pnt = lane & 15;           // point 0..15
        const int l = pnt >> 2;              // level 0..3
        const int cg8 = lane >> 3;           // corner group 0..7
        const unsigned chb = (unsigned)(lane & 7) * 8u;
        const int nvb = p.nqb * 8;

        for (int vb = blockIdx.x; vb < nvb; vb += NB) {
            const int m = vb & 7;            // XCD-pinned (NB%8==0)
            const int qb = (vb >> 3) * 16 + w * 4;

            int q1 = qb + s; if (q1 >= Q) q1 = Q - 1;

            const float logit = h2f(p.logits_h[(size_t)q1 * 128 + m * 16 + pnt]); // *log2e
            const float e = exp2f(logit);    // no max-subtraction: |logit| small
            float sum = e;
            sum += dpp_mov_f32<0x121>(sum);  // row_ror:1
            sum += dpp_mov_f32<0x122>(sum);  // row_ror:2
            sum += dpp_mov_f32<0x124>(sum);  // row_ror:4
            sum += dpp_mov_f32<0x128>(sum);  // row_ror:8 -> full 16-point sum
            const float a = e * fast_rcp(sum);

            const float2 oxy = *(const float2*)(p.offo + (size_t)q1 * 256 + m * 32 + pnt * 2);
            const float2 rxy = *(const float2*)(p.refpt + (size_t)q1 * 8 + l * 2);

            const int Wc = (l == 0) ? 150 : (l == 1) ? 75 : (l == 2) ? 38 : 19;
            const int Hc = (l == 0) ? 100 : (l == 1) ? 50 : (l == 2) ? 25 : 13;
            const int s0 = (l == 0) ? 0 : (l == 1) ? 15000 : (l == 2) ? 18750 : 19700;

            const float x = fmaf(rxy.x, (float)Wc, oxy.x) - 0.5f;
            const float y = fmaf(rxy.y, (float)Hc, oxy.y) - 0.5f;
            const float x0f = floorf(x), y0f = floorf(y);
            const float wx1 = x - x0f, wx0 = 1.f - wx1;
            const float wy1 = y - y0f, wy0 = 1.f - wy1;
            const int x0 = (int)x0f, y0i = (int)y0f;
            const int x1 = x0 + 1, y1 = y0i + 1;

            const bool vx0 = (unsigned)x0  < (unsigned)Wc, vx1 = (unsigned)x1 < (unsigned)Wc;
            const bool vy0 = (unsigned)y0i < (unsigned)Hc, vy1 = (unsigned)y1 < (unsigned)Hc;
            const int xc0 = min(max(x0, 0), Wc - 1), xc1 = min(max(x1, 0), Wc - 1);
            const int yc0 = min(max(y0i, 0), Hc - 1), yc1 = min(max(y1, 0), Hc - 1);
            const int rb0 = s0 + yc0 * Wc, rb1 = s0 + yc1 * Wc;
            const float aw0 = a * wx0, aw1 = a * wx1;

            uint4 pks;   // corner c = cy*2+cx; pack = (f16 wt << 16) | cell
            pks.x = ((unsigned)f2h((vx0 && vy0) ? aw0 * wy0 : 0.f) << 16) | (unsigned)(rb0 + xc0);
            pks.y = ((unsigned)f2h((vx1 && vy0) ? aw1 * wy0 : 0.f) << 16) | (unsigned)(rb0 + xc1);
            pks.z = ((unsigned)f2h((vx0 && vy1) ? aw0 * wy1 : 0.f) << 16) | (unsigned)(rb1 + xc0);
            pks.w = ((unsigned)f2h((vx1 && vy1) ? aw1 * wy1 : 0.f) << 16) | (unsigned)(rb1 + xc1);
            *(uint4*)&pkbuf[w][lane * 4] = pks;

            __syncthreads();   // order LDS handoff (r4 lesson: required fence)

            const char* vb8 = (const char*)(p.value_h + (size_t)m * Q * 32);

#pragma unroll
            for (int sq = 0; sq < 4; ++sq) {
                const int q2 = qb + sq;
                if (q2 >= Q) break;

                unsigned pk[8];
#pragma unroll
                for (int i = 0; i < 8; ++i)
                    pk[i] = pkbuf[w][sq * 64 + i * 8 + cg8];   // broadcast reads

                ushort4 hv[8];
#pragma unroll
                for (int i = 0; i < 8; ++i) {
                    const unsigned off32 = ((pk[i] & 0xffffu) << 6) + chb;  // cell*64B
                    hv[i] = *(const ushort4*)(vb8 + off32);
                }

                float4 acc = {0.f, 0.f, 0.f, 0.f};
#pragma unroll
                for (int i = 0; i < 8; ++i) {
                    const float wt = h2f((unsigned short)(pk[i] >> 16));
                    acc.x = fmaf(h2f(hv[i].x), wt, acc.x);
                    acc.y = fmaf(h2f(hv[i].y), wt, acc.y);
                    acc.z = fmaf(h2f(hv[i].z), wt, acc.z);
                    acc.w = fmaf(h2f(hv[i].w), wt, acc.w);
                }
                acc.x += dpp_mov_f32<0x128>(acc.x);
                acc.y += dpp_mov_f32<0x128>(acc.y);
                acc.z += dpp_mov_f32<0x128>(acc.z);
                acc.w += dpp_mov_f32<0x128>(acc.w);
                acc.x = bfly_add16(acc.x);  acc.y = bfly_add16(acc.y);
                acc.z = bfly_add16(acc.z);  acc.w = bfly_add16(acc.w);
                acc.x = bfly_add32(acc.x);  acc.y = bfly_add32(acc.y);
                acc.z = bfly_add32(acc.z);  acc.w = bfly_add32(acc.w);

                if (lane < 8) {
                    ushort4 hz;
                    hz.x = f2h(acc.x); hz.y = f2h(acc.y);
                    hz.z = f2h(acc.z); hz.w = f2h(acc.w);
                    *(ushort4*)(p.out2 + (size_t)q2 * 256 + m * 32 + lane * 4) = hz;
                }
            }
            __syncthreads();   // guard pkbuf reuse on next virtual block
        }
    }
    __threadfence();
    grid.sync();

    // ===================== phase 4: gemm_out =====================
    {
        unsigned short (*As)[72] = (unsigned short (*)[72])smem;           // [64][72]
        unsigned short (*Bs)[72] = (unsigned short (*)[72])(smem + 9216);  // [64][72]
        const int w = t >> 6, lane = t & 63;
        const int lr = lane & 15, quad = lane >> 4;
        const int rwl = (w & 1) * 32, cwl = (w >> 1) * 32;
        const int a_r = t >> 2, a_k = (t & 3) * 16;
        const int nvb = p.rb * 4;

        for (int vb = blockIdx.x; vb < nvb; vb += NB) {
            const int cby = vb / p.rb;
            const int r0 = (vb - cby * p.rb) * 64, c0 = cby * 64;

            int ar = r0 + a_r; if (ar >= Q) ar = Q - 1;
            const unsigned short* Arow = p.out2 + (size_t)ar * 256;
            const unsigned short* Brow = p.WtOut + (size_t)(c0 + a_r) * 256;

            f32x4 acc[2][2];
#pragma unroll
            for (int i = 0; i < 2; ++i)
#pragma unroll
                for (int j = 0; j < 2; ++j) acc[i][j] = (f32x4){0.f, 0.f, 0.f, 0.f};

            u16x8 av[2], bv[2];
            auto load_chunk = [&](int kc) {
#pragma unroll
                for (int j = 0; j < 2; ++j) {
                    av[j] = *(const u16x8*)(Arow + kc + a_k + j * 8);
                    bv[j] = *(const u16x8*)(Brow + kc + a_k + j * 8);
                }
            };
            auto stage_store = [&]() {
#pragma unroll
                for (int j = 0; j < 2; ++j) {
                    *(u16x8*)&As[a_r][a_k + j * 8] = av[j];
                    *(u16x8*)&Bs[a_r][a_k + j * 8] = bv[j];
                }
            };

            load_chunk(0);
            stage_store();
            __syncthreads();

#pragma unroll
            for (int ch = 0; ch < 4; ++ch) {
                if (ch < 3) load_chunk((ch + 1) * 64);
#pragma unroll
                for (int ks = 0; ks < 2; ++ks) {
                    const int kb = ks * 32 + quad * 8;
                    f16x8 af[2], bfr[2];
#pragma unroll
                    for (int rt = 0; rt < 2; ++rt)
                        af[rt] = *(const f16x8*)&As[rwl + rt * 16 + lr][kb];
#pragma unroll
                    for (int ct = 0; ct < 2; ++ct)
                        bfr[ct] = *(const f16x8*)&Bs[cwl + ct * 16 + lr][kb];
#pragma unroll
                    for (int rt = 0; rt < 2; ++rt)
#pragma unroll
                        for (int ct = 0; ct < 2; ++ct)
                            acc[rt][ct] = __builtin_amdgcn_mfma_f32_16x16x32_f16(
                                af[rt], bfr[ct], acc[rt][ct], 0, 0, 0);
                }
                if (ch < 3) { __syncthreads(); stage_store(); __syncthreads(); }
            }

#pragma unroll
            for (int ct = 0; ct < 2; ++ct) {
                const int col = c0 + cwl + ct * 16 + lr;
                const float bb = p.b_out[col];
#pragma unroll
                for (int rt = 0; rt < 2; ++rt)
#pragma unroll
                    for (int reg = 0; reg < 4; ++reg) {
                        const int r = r0 + rwl + rt * 16 + quad * 4 + reg;
                        if (r < Q) p.out[(size_t)r * 256 + col] = acc[rt][ct][reg] + bb;
                    }
            }
            __syncthreads();   // guard LDS reuse on next virtual block
        }
    }
}

// ===========================================================================
// Fallback path: the proven r5 kernels (identical math to the fused phases).
// ===========================================================================
__global__ __launch_bounds__(256) void prep_k(
    const float* __restrict__ Wv, const float* __restrict__ Wo,
    const float* __restrict__ Wa, const float* __restrict__ Wq,
    unsigned short* __restrict__ HV, unsigned short* __restrict__ HO,
    unsigned short* __restrict__ HA, unsigned short* __restrict__ HQ,
    const float* __restrict__ inflat, const float* __restrict__ query,
    unsigned short* __restrict__ inflat_h, unsigned short* __restrict__ query_h,
    int QD)
{
    int b = blockIdx.x;
    if (b >= 56) {
        const int f = ((b - 56) * 256 + (int)threadIdx.x) * 8;
        if (f < 2 * QD) {
            const float* src; unsigned short* dst; int i;
            if (f < QD) { src = inflat; dst = inflat_h; i = f; }
            else        { src = query;  dst = query_h;  i = f - QD; }
            const float4 v0 = *(const float4*)(src + i);
            const float4 v1 = *(const float4*)(src + i + 4);
            u16x8 h;
            h[0] = (short)f2h(v0.x); h[1] = (short)f2h(v0.y);
            h[2] = (short)f2h(v0.z); h[3] = (short)f2h(v0.w);
            h[4] = (short)f2h(v1.x); h[5] = (short)f2h(v1.y);
            h[6] = (short)f2h(v1.z); h[7] = (short)f2h(v1.w);
            *(u16x8*)(dst + i) = h;
        }
        return;
    }

    __shared__ unsigned short tH[64][68];
    const float* W; unsigned short* H; int NC;
    if (b < 16)      { W = Wv; H = HV; NC = 256; }
    else if (b < 32) { W = Wo; H = HO; NC = 256; b -= 16; }
    else if (b < 40) { W = Wa; H = HA; NC = 128; b -= 32; }
    else             { W = Wq; H = HQ; NC = 256; b -= 40; }
    const int k0 = (b & 3) * 64, c0 = (b >> 2) * 64;

    const int t = threadIdx.x;
    const int cl = t & 63;
#pragma unroll
    for (int i = 0; i < 16; ++i) {
        const int kl = (t >> 6) * 16 + i;
        tH[cl][kl] = f2h(W[(size_t)(k0 + kl) * NC + c0 + cl]);
    }
    __syncthreads();
    const int kl = t & 63;
#pragma unroll
    for (int i = 0; i < 16; ++i) {
        const int cl2 = (t >> 6) * 16 + i;
        H[(size_t)(c0 + cl2) * 256 + k0 + kl] = tH[cl2][kl];
    }
}

__global__ __launch_bounds__(256) void gemm_in_k(
    const unsigned short* __restrict__ inflat_h,
    const unsigned short* __restrict__ query_h,
    const unsigned short* __restrict__ BtVal,
    const unsigned short* __restrict__ BtOff,
    const unsigned short* __restrict__ BtAttn,
    const float* __restrict__ b_val, const float* __restrict__ b_off,
    const float* __restrict__ b_attn,
    unsigned short* __restrict__ value_h, float* __restrict__ offo,
    unsigned short* __restrict__ logits_h, int Q, const unsigned char* __restrict__ mask)
{
    __shared__ unsigned short As[64][72];
    __shared__ unsigned short Bs[128][72];

    const int y = blockIdx.y;
    const unsigned short* A; const unsigned short* Bt; const float* bias; int c0;
    if (y < 2)      { A = inflat_h; Bt = BtVal;  bias = b_val;  c0 = y * 128; }
    else if (y < 4) { A = query_h;  Bt = BtOff;  bias = b_off;  c0 = (y - 2) * 128; }
    else            { A = query_h;  Bt = BtAttn; bias = b_attn; c0 = 0; }

    const int t = threadIdx.x;
    const int w = t >> 6, lane = t & 63;
    const int lr = lane & 15, quad = lane >> 4;
    const int rwl = (w & 1) * 32, cwl = (w >> 1) * 64;
    const int r0 = blockIdx.x * 64;

    const int a_r = t >> 2, a_q = (t & 3) * 16;
    const int b_c = t >> 1, b_k = (t & 1) * 32;

    int ar = r0 + a_r; if (ar >= Q) ar = Q - 1;
    const unsigned short* Arow = A + (size_t)ar * 256;
    const unsigned short* Brow = Bt + (size_t)(c0 + b_c) * 256;

    f32x4 acc[2][4];
#pragma unroll
    for (int i = 0; i < 2; ++i)
#pragma unroll
        for (int j = 0; j < 4; ++j) acc[i][j] = (f32x4){0.f, 0.f, 0.f, 0.f};

    u16x8 av[2], bv[4];
    auto load_chunk = [&](int kc) {
#pragma unroll
        for (int j = 0; j < 2; ++j) av[j] = *(const u16x8*)(Arow + kc + a_q + j * 8);
#pragma unroll
        for (int j = 0; j < 4; ++j) bv[j] = *(const u16x8*)(Brow + kc + b_k + j * 8);
    };
    auto stage_store = [&]() {
#pragma unroll
        for (int j = 0; j < 2; ++j) *(u16x8*)&As[a_r][a_q + j * 8] = av[j];
#pragma unroll
        for (int j = 0; j < 4; ++j) *(u16x8*)&Bs[b_c][b_k + j * 8] = bv[j];
    };

    load_chunk(0);
    stage_store();
    __syncthreads();

#pragma unroll
    for (int ch = 0; ch < 4; ++ch) {
        if (ch < 3) load_chunk((ch + 1) * 64);
#pragma unroll
        for (int ks = 0; ks < 2; ++ks) {
            const int kb = ks * 32 + quad * 8;
            f16x8 af[2], bfr[4];
#pragma unroll
            for (int rt = 0; rt < 2; ++rt)
                af[rt] = *(const f16x8*)&As[rwl + rt * 16 + lr][kb];
#pragma unroll
            for (int ct = 0; ct < 4; ++ct)
                bfr[ct] = *(const f16x8*)&Bs[cwl + ct * 16 + lr][kb];
#pragma unroll
            for (int rt = 0; rt < 2; ++rt)
#pragma unroll
                for (int ct = 0; ct < 4; ++ct)
                    acc[rt][ct] = __builtin_amdgcn_mfma_f32_16x16x32_f16(
                        af[rt], bfr[ct], acc[rt][ct], 0, 0, 0);
        }
        if (ch < 3) { __syncthreads(); stage_store(); __syncthreads(); }
    }

#pragma unroll
    for (int ct = 0; ct < 4; ++ct) {
        const int col = c0 + cwl + ct * 16 + lr;
        const float bb = bias[col];
#pragma unroll
        for (int rt = 0; rt < 2; ++rt)
#pragma unroll
            for (int reg = 0; reg < 4; ++reg) {
                const int r = r0 + rwl + rt * 16 + quad * 4 + reg;
                if (r < Q) {
                    float v = acc[rt][ct][reg] + bb;
                    if (y < 2) {
                        if (mask && mask[r]) v = 0.f;
                        value_h[((size_t)(col >> 5) * Q + r) * 32 + (col & 31)] = f2h(v);
                    } else if (y < 4) {
                        offo[(size_t)r * 256 + col] = v;
                    } else {
                        logits_h[(size_t)r * 128 + col] = f2h(v * 1.44269504f);
                    }
                }
            }
    }
}

__global__ __launch_bounds__(256) void msda_k(
    const unsigned short* __restrict__ value, const float* __restrict__ off,
    const unsigned short* __restrict__ logits, const float* __restrict__ ref,
    unsigned short* __restrict__ out2, int Q)
{
    __shared__ unsigned pkbuf[4][256];

    const int t = threadIdx.x;
    const int w = t >> 6;
    const int lane = t & 63;
    const int m = blockIdx.x & 7;
    const int qb = (blockIdx.x >> 3) * 16 + w * 4;

    const int s = lane >> 4;
    const int p = lane & 15;
    const int l = p >> 2;

    int q1 = qb + s; if (q1 >= Q) q1 = Q - 1;

    const float logit = h2f(logits[(size_t)q1 * 128 + m * 16 + p]);
    const float e = exp2f(logit);
    float sum = e;
    sum += dpp_mov_f32<0x121>(sum);
    sum += dpp_mov_f32<0x122>(sum);
    sum += dpp_mov_f32<0x124>(sum);
    sum += dpp_mov_f32<0x128>(sum);
    const float a = e * fast_rcp(sum);

    const float2 oxy = *(const float2*)(off + (size_t)q1 * 256 + m * 32 + p * 2);
    const float2 rxy = *(const float2*)(ref + (size_t)q1 * 8 + l * 2);

    const int Wc = (l == 0) ? 150 : (l == 1) ? 75 : (l == 2) ? 38 : 19;
    const int Hc = (l == 0) ? 100 : (l == 1) ? 50 : (l == 2) ? 25 : 13;
    const int s0 = (l == 0) ? 0 : (l == 1) ? 15000 : (l == 2) ? 18750 : 19700;

    const float x = fmaf(rxy.x, (float)Wc, oxy.x) - 0.5f;
    const float y = fmaf(rxy.y, (float)Hc, oxy.y) - 0.5f;
    const float x0f = floorf(x), y0f = floorf(y);
    const float wx1 = x - x0f, wx0 = 1.f - wx1;
    const float wy1 = y - y0f, wy0 = 1.f - wy1;
    const int x0 = (int)x0f, y0i = (int)y0f;
    const int x1 = x0 + 1, y1 = y0i + 1;

    const bool vx0 = (unsigned)x0  < (unsigned)Wc, vx1 = (unsigned)x1 < (unsigned)Wc;
    const bool vy0 = (unsigned)y0i < (unsigned)Hc, vy1 = (unsigned)y1 < (unsigned)Hc;
    const int xc0 = min(max(x0, 0), Wc - 1), xc1 = min(max(x1, 0), Wc - 1);
    const int yc0 = min(max(y0i, 0), Hc - 1), yc1 = min(max(y1, 0), Hc - 1);
    const int rb0 = s0 + yc0 * Wc, rb1 = s0 + yc1 * Wc;
    const float aw0 = a * wx0, aw1 = a * wx1;

    uint4 pks;
    pks.x = ((unsigned)f2h((vx0 && vy0) ? aw0 * wy0 : 0.f) << 16) | (unsigned)(rb0 + xc0);
    pks.y = ((unsigned)f2h((vx1 && vy0) ? aw1 * wy0 : 0.f) << 16) | (unsigned)(rb0 + xc1);
    pks.z = ((unsigned)f2h((vx0 && vy1) ? aw0 * wy1 : 0.f) << 16) | (unsigned)(rb1 + xc0);
    pks.w = ((unsigned)f2h((vx1 && vy1) ? aw1 * wy1 : 0.f) << 16) | (unsigned)(rb1 + xc1);
    *(uint4*)&pkbuf[w][lane * 4] = pks;

    __syncthreads();

    const int cg8 = lane >> 3;
    const unsigned chb = (unsigned)(lane & 7) * 8u;
    const char* vb = (const char*)(value + (size_t)m * Q * 32);

#pragma unroll
    for (int sq = 0; sq < 4; ++sq) {
        const int q2 = qb + sq;
        if (q2 >= Q) break;

        unsigned pk[8];
#pragma unroll
        for (int i = 0; i < 8; ++i)
            pk[i] = pkbuf[w][sq * 64 + i * 8 + cg8];

        ushort4 hv[8];
#pragma unroll
        for (int i = 0; i < 8; ++i) {
            const unsigned off32 = ((pk[i] & 0xffffu) << 6) + chb;
            hv[i] = *(const ushort4*)(vb + off32);
        }

        float4 acc = {0.f, 0.f, 0.f, 0.f};
#pragma unroll
        for (int i = 0; i < 8; ++i) {
            const float wt = h2f((unsigned short)(pk[i] >> 16));
            acc.x = fmaf(h2f(hv[i].x), wt, acc.x);
            acc.y = fmaf(h2f(hv[i].y), wt, acc.y);
            acc.z = fmaf(h2f(hv[i].z), wt, acc.z);
            acc.w = fmaf(h2f(hv[i].w), wt, acc.w);
        }
        acc.x += dpp_mov_f32<0x128>(acc.x);
        acc.y += dpp_mov_f32<0x128>(acc.y);
        acc.z += dpp_mov_f32<0x128>(acc.z);
        acc.w += dpp_mov_f32<0x128>(acc.w);
        acc.x = bfly_add16(acc.x);  acc.y = bfly_add16(acc.y);
        acc.z = bfly_add16(acc.z);  acc.w = bfly_add16(acc.w);
        acc.x = bfly_add32(acc.x);  acc.y = bfly_add32(acc.y);
        acc.z = bfly_add32(acc.z);  acc.w = bfly_add32(acc.w);

        if (lane < 8) {
            ushort4 hz;
            hz.x = f2h(acc.x); hz.y = f2h(acc.y);
            hz.z = f2h(acc.z); hz.w = f2h(acc.w);
            *(ushort4*)(out2 + (size_t)q2 * 256 + m * 32 + lane * 4) = hz;
        }
    }
}

__global__ __launch_bounds__(256) void gemm_out_k(
    const unsigned short* __restrict__ A, const unsigned short* __restrict__ Bt,
    const float* __restrict__ bias, float* __restrict__ C, int Q)
{
    __shared__ unsigned short As[64][72];
    __shared__ unsigned short Bs[64][72];

    const int t = threadIdx.x;
    const int w = t >> 6, lane = t & 63;
    const int lr = lane & 15, quad = lane >> 4;
    const int rwl = (w & 1) * 32, cwl = (w >> 1) * 32;
    const int r0 = blockIdx.x * 64, c0 = blockIdx.y * 64;

    const int a_r = t >> 2, a_k = (t & 3) * 16;

    int ar = r0 + a_r; if (ar >= Q) ar = Q - 1;
    const unsigned short* Arow = A + (size_t)ar * 256;
    const unsigned short* Brow = Bt + (size_t)(c0 + a_r) * 256;

    f32x4 acc[2][2];
#pragma unroll
    for (int i = 0; i < 2; ++i)
#pragma unroll
        for (int j = 0; j < 2; ++j) acc[i][j] = (f32x4){0.f, 0.f, 0.f, 0.f};

    u16x8 av[2], bv[2];
    auto load_chunk = [&](int kc) {
#pragma unroll
        for (int j = 0; j < 2; ++j) {
            av[j] = *(const u16x8*)(Arow + kc + a_k + j * 8);
            bv[j] = *(const u16x8*)(Brow + kc + a_k + j * 8);
        }
    };
    auto stage_store = [&]() {
#pragma unroll
        for (int j = 0; j < 2; ++j) {
            *(u16x8*)&As[a_r][a_k + j * 8] = av[j];
            *(u16x8*)&Bs[a_r][a_k + j * 8] = bv[j];
        }
    };

    load_chunk(0);
    stage_store();
    __syncthreads();

#pragma unroll
    for (int ch = 0; ch < 4; ++ch) {
        if (ch < 3) load_chunk((ch + 1) * 64);
#pragma unroll
        for (int ks = 0; ks < 2; ++ks) {
            const int kb = ks * 32 + quad * 8;
            f16x8 af[2], bfr[2];
#pragma unroll
            for (int rt = 0; rt < 2; ++rt)
                af[rt] = *(const f16x8*)&As[rwl + rt * 16 + lr][kb];
#pragma unroll
            for (int ct = 0; ct < 2; ++ct)
                bfr[ct] = *(const f16x8*)&Bs[cwl + ct * 16 + lr][kb];
#pragma unroll
            for (int rt = 0; rt < 2; ++rt)
#pragma unroll
                for (int ct = 0; ct < 2; ++ct)
                    acc[rt][ct] = __builtin_amdgcn_mfma_f32_16x16x32_f16(
                        af[rt], bfr[ct], acc[rt][ct], 0, 0, 0);
        }
        if (ch < 3) { __syncthreads(); stage_store(); __syncthreads(); }
    }

#pragma unroll
    for (int ct = 0; ct < 2; ++ct) {
        const int col = c0 + cwl + ct * 16 + lr;
        const float bb = bias[col];
#pragma unroll
        for (int rt = 0; rt < 2; ++rt)
#pragma unroll
            for (int reg = 0; reg < 4; ++reg) {
                const int r = r0 + rwl + rt * 16 + quad * 4 + reg;
                if (r < Q) C[(size_t)r * 256 + col] = acc[rt][ct][reg] + bb;
            }
    }
}

// ---------------------------------------------------------------------------
extern "C" void kernel_launch(void* const* d_in, const int* in_sizes, int n_in,
                              void* d_out, int out_size, void* d_ws, size_t ws_size,
                              hipStream_t stream)
{
    Params p;
    p.query  = (const float*)d_in[0];
    p.refpt  = (const float*)d_in[1];
    p.inflat = (const float*)d_in[2];
    p.mask   = (const unsigned char*)d_in[3];
    p.W_off  = (const float*)d_in[4];
    p.b_off  = (const float*)d_in[5];
    p.W_attn = (const float*)d_in[6];
    p.b_attn = (const float*)d_in[7];
    p.W_val  = (const float*)d_in[8];
    p.b_val  = (const float*)d_in[9];
    p.W_out  = (const float*)d_in[10];
    p.b_out  = (const float*)d_in[11];
    p.out    = (float*)d_out;

    const int Q = in_sizes[0] / DMODEL;  // 19947
    const int QD = Q * DMODEL;
    p.Q = Q; p.QD = QD;
    p.rb  = (Q + 63) / 64;               // 312
    p.na  = (2 * QD + 2047) / 2048;      // A-convert virtual blocks
    p.nqb = (Q + 15) / 16;               // msda virtual q-blocks

    p.value_h  = (unsigned short*)d_ws;                      // Q*256, m-major
    p.offo     = (float*)(p.value_h + (size_t)QD);           // Q*256
    p.logits_h = (unsigned short*)(p.offo + (size_t)QD);     // Q*128
    p.out2     = p.logits_h + (size_t)Q * 128;               // Q*256
    p.inflat_h = p.out2 + (size_t)QD;
    p.query_h  = p.inflat_h + (size_t)QD;
    p.WtVal    = p.query_h + (size_t)QD;
    p.WtOff    = p.WtVal  + 65536;
    p.WtAttn   = p.WtOff  + 65536;       // 128*256
    p.WtOut    = p.WtAttn + 32768;

    // One-time: runtime-validated cooperative grid size (multiple of 8; 0 = off)
    static int s_coop_blocks = -1;
    if (s_coop_blocks < 0) {
        int perCU = 0, ncu = 0, dev = 0;
        if (hipGetDevice(&dev) != hipSuccess) dev = 0;
        if (hipOccupancyMaxActiveBlocksPerMultiprocessor(&perCU, fused_k, 256, 0)
                != hipSuccess) perCU = 0;
        if (hipDeviceGetAttribute(&ncu, hipDeviceAttributeMultiprocessorCount, dev)
                != hipSuccess) ncu = 0;
        int nb = perCU * ncu;
        if (nb > 1024) nb = 1024;
        nb &= ~7;                        // keep m = vb&7 XCD-pinning valid
        s_coop_blocks = nb;
    }

    bool done = false;
    if (s_coop_blocks >= 8) {
        void* args[] = { &p };
        if (hipLaunchCooperativeKernel((void*)fused_k, dim3(s_coop_blocks),
                                       dim3(256), args, 0, stream) == hipSuccess)
            done = true;
    }

    if (!done) {
        // r5-proven 4-dispatch fallback (bitwise-identical results)
        const int rb = p.rb;
        const int na = p.na;
        const int nqb = p.nqb;
        prep_k<<<56 + na, 256, 0, stream>>>(p.W_val, p.W_off, p.W_attn, p.W_out,
                                            p.WtVal, p.WtOff, p.WtAttn, p.WtOut,
                                            p.inflat, p.query, p.inflat_h, p.query_h, QD);
        gemm_in_k<<<dim3(rb, 5), 256, 0, stream>>>(
            p.inflat_h, p.query_h, p.WtVal, p.WtOff, p.WtAttn,
            p.b_val, p.b_off, p.b_attn,
            p.value_h, p.offo, p.logits_h, Q, p.mask);
        msda_k<<<nqb * 8, 256, 0, stream>>>(p.value_h, p.offo, p.logits_h,
                                            p.refpt, p.out2, Q);
        gemm_out_k<<<dim3(rb, 4), 256, 0, stream>>>(p.out2, p.WtOut, p.b_out,
                                                    p.out, Q);
    }
}

// Round 11
// 187.345 us; speedup vs baseline: 3.0602x; 3.0602x over previous
//
#include <hip/hip_runtime.h>

// Deformable-DETR MSDeformAttn, Q=19947, D=256, M=8, L=4, P=4, DH=32.
// ROUND 11: restore the verified-best r5 configuration (185.5us).
// Experiment ledger: LDS-free GEMMs (r6: latency chain, 3% MfmaUtil),
// full up-front prefetch (r7: -15us regression), msda+proj fusion (r8:
// lost m-pinned L2 locality, 4x FETCH), cooperative single-dispatch
// (r9/r10: grid.sync spin across non-coherent XCD L2s -> 573us, all pipes
// idle). All falsified; 4-dispatch r5 stands as the optimum found.
//   prep: weight transposes + A f32->fp16 (traffic-roofline bound ~12-15us)
//   gemm_in: LDS-staged f16 MFMA, 64x128 tile, interleaved prefetch;
//            value fp16 M-MAJOR [m][cell][32], off f32, logits fp16*log2e
//   msda: 4 q's/wave, DPP-only softmax, packed LDS corner handoff (+barrier,
//         r4 race lesson), m-pinned gathers (L2-resident 1.27MB slices),
//         permlane-swap reductions
//   gemm_out: LDS-staged f16 MFMA, 64x64 tiles, grid (312,4)

#define DMODEL 256

typedef __attribute__((ext_vector_type(8))) short u16x8;      // raw 16-bit staging
typedef __attribute__((ext_vector_type(8))) _Float16 f16x8;   // MFMA A/B fragment
typedef __attribute__((ext_vector_type(4))) float f32x4;

static __device__ inline unsigned short f2h(float f) {
    return __builtin_bit_cast(unsigned short, (_Float16)f);   // v_cvt_f16_f32 (RNE)
}
static __device__ inline float h2f(unsigned short h) {
    return (float)__builtin_bit_cast(_Float16, h);
}
static __device__ inline float fast_rcp(float x) {
#if __has_builtin(__builtin_amdgcn_rcpf)
    return __builtin_amdgcn_rcpf(x);
#else
    return 1.f / x;
#endif
}
// DPP cross-lane move within 16-lane rows (VALU). row_ror:n ctrl = 0x120|n.
template<int CTRL>
static __device__ inline float dpp_mov_f32(float x) {
    return __builtin_bit_cast(float,
        __builtin_amdgcn_mov_dpp(__builtin_bit_cast(int, x), CTRL, 0xf, 0xf, false));
}
// Butterfly add across lane^16 / lane^32 via v_permlane*_swap (VALU, no DS).
static __device__ inline float bfly_add16(float x) {
    float a = x, b = x;
    asm("v_permlane16_swap_b32 %0, %1" : "+v"(a), "+v"(b));
    return a + b;
}
static __device__ inline float bfly_add32(float x) {
    float a = x, b = x;
    asm("v_permlane32_swap_b32 %0, %1" : "+v"(a), "+v"(b));
    return a + b;
}

// ---------------------------------------------------------------------------
// prep_k: weight transposes (blocks 0..55) + inflat/query fp32->fp16 convert
// (blocks 56..). W[k][c] fp32 -> Wt[c][k] fp16.
// ---------------------------------------------------------------------------
__global__ __launch_bounds__(256) void prep_k(
    const float* __restrict__ Wv, const float* __restrict__ Wo,
    const float* __restrict__ Wa, const float* __restrict__ Wq,
    unsigned short* __restrict__ HV, unsigned short* __restrict__ HO,
    unsigned short* __restrict__ HA, unsigned short* __restrict__ HQ,
    const float* __restrict__ inflat, const float* __restrict__ query,
    unsigned short* __restrict__ inflat_h, unsigned short* __restrict__ query_h,
    int QD)
{
    int b = blockIdx.x;
    if (b >= 56) {
        // A conversion: 8 consecutive floats per thread.
        const int f = ((b - 56) * 256 + (int)threadIdx.x) * 8;
        if (f < 2 * QD) {
            const float* src; unsigned short* dst; int i;
            if (f < QD) { src = inflat; dst = inflat_h; i = f; }
            else        { src = query;  dst = query_h;  i = f - QD; }
            const float4 v0 = *(const float4*)(src + i);
            const float4 v1 = *(const float4*)(src + i + 4);
            u16x8 h;
            h[0] = (short)f2h(v0.x); h[1] = (short)f2h(v0.y);
            h[2] = (short)f2h(v0.z); h[3] = (short)f2h(v0.w);
            h[4] = (short)f2h(v1.x); h[5] = (short)f2h(v1.y);
            h[6] = (short)f2h(v1.z); h[7] = (short)f2h(v1.w);
            *(u16x8*)(dst + i) = h;
        }
        return;
    }

    __shared__ unsigned short tH[64][68];

    const float* W; unsigned short* H; int NC;
    if (b < 16)      { W = Wv; H = HV; NC = 256; }
    else if (b < 32) { W = Wo; H = HO; NC = 256; b -= 16; }
    else if (b < 40) { W = Wa; H = HA; NC = 128; b -= 32; }
    else             { W = Wq; H = HQ; NC = 256; b -= 40; }
    const int k0 = (b & 3) * 64, c0 = (b >> 2) * 64;

    const int t = threadIdx.x;
    const int cl = t & 63;
#pragma unroll
    for (int i = 0; i < 16; ++i) {
        const int kl = (t >> 6) * 16 + i;
        tH[cl][kl] = f2h(W[(size_t)(k0 + kl) * NC + c0 + cl]);
    }
    __syncthreads();
    const int kl = t & 63;
#pragma unroll
    for (int i = 0; i < 16; ++i) {
        const int cl2 = (t >> 6) * 16 + i;
        H[(size_t)(c0 + cl2) * 256 + k0 + kl] = tH[cl2][kl];
    }
}

// ---------------------------------------------------------------------------
// gemm_in_k: the three input GEMMs fused; A pre-converted fp16 (pure-copy
// staging, no conversions in the hot loop). grid (312, 5):
// y 0-1 value (fp16 m-major), y 2-3 off (f32), y 4 logits (fp16, *log2e).
// 64x128 tile / 256 threads; wave = 32x64 quadrant; interleaved prefetch.
// ---------------------------------------------------------------------------
__global__ __launch_bounds__(256) void gemm_in_k(
    const unsigned short* __restrict__ inflat_h,
    const unsigned short* __restrict__ query_h,
    const unsigned short* __restrict__ BtVal,
    const unsigned short* __restrict__ BtOff,
    const unsigned short* __restrict__ BtAttn,
    const float* __restrict__ b_val, const float* __restrict__ b_off,
    const float* __restrict__ b_attn,
    unsigned short* __restrict__ value_h, float* __restrict__ offo,
    unsigned short* __restrict__ logits_h, int Q, const unsigned char* __restrict__ mask)
{
    __shared__ unsigned short As[64][72];    // [row][k]
    __shared__ unsigned short Bs[128][72];   // [col][k]

    const int y = blockIdx.y;
    const unsigned short* A; const unsigned short* Bt; const float* bias; int c0;
    if (y < 2)      { A = inflat_h; Bt = BtVal;  bias = b_val;  c0 = y * 128; }
    else if (y < 4) { A = query_h;  Bt = BtOff;  bias = b_off;  c0 = (y - 2) * 128; }
    else            { A = query_h;  Bt = BtAttn; bias = b_attn; c0 = 0; }

    const int t = threadIdx.x;
    const int w = t >> 6, lane = t & 63;
    const int lr = lane & 15, quad = lane >> 4;
    const int rwl = (w & 1) * 32, cwl = (w >> 1) * 64;
    const int r0 = blockIdx.x * 64;

    const int a_r = t >> 2, a_q = (t & 3) * 16;   // A: row, 16-short k-span
    const int b_c = t >> 1, b_k = (t & 1) * 32;   // B: col, 32-short k-span

    int ar = r0 + a_r; if (ar >= Q) ar = Q - 1;   // clamp: dup row, never stored
    const unsigned short* Arow = A + (size_t)ar * 256;
    const unsigned short* Brow = Bt + (size_t)(c0 + b_c) * 256;

    f32x4 acc[2][4];
#pragma unroll
    for (int i = 0; i < 2; ++i)
#pragma unroll
        for (int j = 0; j < 4; ++j) acc[i][j] = (f32x4){0.f, 0.f, 0.f, 0.f};

    u16x8 av[2], bv[4];
    auto load_chunk = [&](int kc) {
#pragma unroll
        for (int j = 0; j < 2; ++j) av[j] = *(const u16x8*)(Arow + kc + a_q + j * 8);
#pragma unroll
        for (int j = 0; j < 4; ++j) bv[j] = *(const u16x8*)(Brow + kc + b_k + j * 8);
    };
    auto stage_store = [&]() {
#pragma unroll
        for (int j = 0; j < 2; ++j) *(u16x8*)&As[a_r][a_q + j * 8] = av[j];
#pragma unroll
        for (int j = 0; j < 4; ++j) *(u16x8*)&Bs[b_c][b_k + j * 8] = bv[j];
    };

    load_chunk(0);
    stage_store();
    __syncthreads();

#pragma unroll
    for (int ch = 0; ch < 4; ++ch) {
        if (ch < 3) load_chunk((ch + 1) * 64);   // in flight during MFMA
#pragma unroll
        for (int ks = 0; ks < 2; ++ks) {
            const int kb = ks * 32 + quad * 8;
            f16x8 af[2], bfr[4];
#pragma unroll
            for (int rt = 0; rt < 2; ++rt)
                af[rt] = *(const f16x8*)&As[rwl + rt * 16 + lr][kb];
#pragma unroll
            for (int ct = 0; ct < 4; ++ct)
                bfr[ct] = *(const f16x8*)&Bs[cwl + ct * 16 + lr][kb];
#pragma unroll
            for (int rt = 0; rt < 2; ++rt)
#pragma unroll
                for (int ct = 0; ct < 4; ++ct)
                    acc[rt][ct] = __builtin_amdgcn_mfma_f32_16x16x32_f16(
                        af[rt], bfr[ct], acc[rt][ct], 0, 0, 0);
        }
        if (ch < 3) { __syncthreads(); stage_store(); __syncthreads(); }
    }

    // epilogue: C/D layout col=lane&15, row=quad*4+reg
#pragma unroll
    for (int ct = 0; ct < 4; ++ct) {
        const int col = c0 + cwl + ct * 16 + lr;
        const float bb = bias[col];
#pragma unroll
        for (int rt = 0; rt < 2; ++rt)
#pragma unroll
            for (int reg = 0; reg < 4; ++reg) {
                const int r = r0 + rwl + rt * 16 + quad * 4 + reg;
                if (r < Q) {
                    float v = acc[rt][ct][reg] + bb;
                    if (y < 2) {
                        if (mask && mask[r]) v = 0.f;
                        // m-major: value[m][cell][ch], m = col>>5, ch = col&31
                        value_h[((size_t)(col >> 5) * Q + r) * 32 + (col & 31)] = f2h(v);
                    } else if (y < 4) {
                        offo[(size_t)r * 256 + col] = v;
                    } else {
                        logits_h[(size_t)r * 128 + col] = f2h(v * 1.44269504f);
                    }
                }
            }
    }
}

// ---------------------------------------------------------------------------
// msda_k: fused softmax + bilinear sampling + weighted accumulation.
// Block = one m (XCD-pinned: m = blockIdx&7) x 16 q's; each 64-lane wave
// handles FOUR q's (lane = qslot*16 + point).
// Phase 1: fp16 logit -> exp2 (pre-scaled), denom via DPP row_ror 1/2/4/8;
//   all 4 corner (cell, f16 wt) packs; one ds_write_b128 at word s*64+k.
// __syncthreads() — REQUIRED (r4 raced: type-punned store vs loads, no fence).
// Phase 2 (per q-slot): 8 broadcast ds_read of packs; 8 independent 8B fp16
//   gathers off block-uniform m-slice base; fma accumulate; reduce = DPP
//   ror8 + permlane16/32 swaps (all VALU); fp16 out2 from lanes 0-7.
// ---------------------------------------------------------------------------
__global__ __launch_bounds__(256) void msda_k(
    const unsigned short* __restrict__ value, const float* __restrict__ off,
    const unsigned short* __restrict__ logits, const float* __restrict__ ref,
    unsigned short* __restrict__ out2, int Q)
{
    __shared__ unsigned pkbuf[4][256];       // [wave][qslot*64 + corner]

    const int t = threadIdx.x;
    const int w = t >> 6;
    const int lane = t & 63;
    const int m = blockIdx.x & 7;            // XCD-pinned m-slice
    const int qb = (blockIdx.x >> 3) * 16 + w * 4;   // wave's first q

    // ---- phase 1: lane = qslot*16 + point ----
    const int s = lane >> 4;             // q-slot 0..3
    const int p = lane & 15;             // point 0..15
    const int l = p >> 2;                // level 0..3

    int q1 = qb + s; if (q1 >= Q) q1 = Q - 1;   // clamp: dup q, stores guarded

    const float logit = h2f(logits[(size_t)q1 * 128 + m * 16 + p]); // *log2e
    const float e = exp2f(logit);        // no max-subtraction: |logit| small
    float sum = e;
    sum += dpp_mov_f32<0x121>(sum);      // row_ror:1
    sum += dpp_mov_f32<0x122>(sum);      // row_ror:2
    sum += dpp_mov_f32<0x124>(sum);      // row_ror:4
    sum += dpp_mov_f32<0x128>(sum);      // row_ror:8 -> full 16-point sum
    const float a = e * fast_rcp(sum);

    const float2 oxy = *(const float2*)(off + (size_t)q1 * 256 + m * 32 + p * 2);
    const float2 rxy = *(const float2*)(ref + (size_t)q1 * 8 + l * 2);

    const int Wc = (l == 0) ? 150 : (l == 1) ? 75 : (l == 2) ? 38 : 19;
    const int Hc = (l == 0) ? 100 : (l == 1) ? 50 : (l == 2) ? 25 : 13;
    const int s0 = (l == 0) ? 0 : (l == 1) ? 15000 : (l == 2) ? 18750 : 19700;

    // affine collapse is exact; +-2 clip never binds (|ox|<=4.5 -> |gx|<=1.5)
    const float x = fmaf(rxy.x, (float)Wc, oxy.x) - 0.5f;
    const float y = fmaf(rxy.y, (float)Hc, oxy.y) - 0.5f;
    const float x0f = floorf(x), y0f = floorf(y);
    const float wx1 = x - x0f, wx0 = 1.f - wx1;
    const float wy1 = y - y0f, wy0 = 1.f - wy1;
    const int x0 = (int)x0f, y0i = (int)y0f;
    const int x1 = x0 + 1, y1 = y0i + 1;

    const bool vx0 = (unsigned)x0  < (unsigned)Wc, vx1 = (unsigned)x1 < (unsigned)Wc;
    const bool vy0 = (unsigned)y0i < (unsigned)Hc, vy1 = (unsigned)y1 < (unsigned)Hc;
    const int xc0 = min(max(x0, 0), Wc - 1), xc1 = min(max(x1, 0), Wc - 1);
    const int yc0 = min(max(y0i, 0), Hc - 1), yc1 = min(max(y1, 0), Hc - 1);
    const int rb0 = s0 + yc0 * Wc, rb1 = s0 + yc1 * Wc;
    const float aw0 = a * wx0, aw1 = a * wx1;

    uint4 pks;   // corner c = cy*2+cx; pack = (f16 wt << 16) | cell
    pks.x = ((unsigned)f2h((vx0 && vy0) ? aw0 * wy0 : 0.f) << 16) | (unsigned)(rb0 + xc0);
    pks.y = ((unsigned)f2h((vx1 && vy0) ? aw1 * wy0 : 0.f) << 16) | (unsigned)(rb0 + xc1);
    pks.z = ((unsigned)f2h((vx0 && vy1) ? aw0 * wy1 : 0.f) << 16) | (unsigned)(rb1 + xc0);
    pks.w = ((unsigned)f2h((vx1 && vy1) ? aw1 * wy1 : 0.f) << 16) | (unsigned)(rb1 + xc1);
    // corner k of slot s lands at word s*64 + k  ((k>>2)*4 + (k&3) == k)
    *(uint4*)&pkbuf[w][lane * 4] = pks;

    __syncthreads();   // order LDS handoff (fixes r4 race)

    // ---- phase 2: per q-slot gather + accumulate ----
    const int cg = lane >> 3;                          // corner group 0..7
    const unsigned chb = (unsigned)(lane & 7) * 8u;    // channel-quad byte off
    const char* vb = (const char*)(value + (size_t)m * Q * 32);  // m-slice base

#pragma unroll
    for (int sq = 0; sq < 4; ++sq) {
        const int q2 = qb + sq;
        if (q2 >= Q) break;

        unsigned pk[8];
#pragma unroll
        for (int i = 0; i < 8; ++i)
            pk[i] = pkbuf[w][sq * 64 + i * 8 + cg];    // broadcast reads

        ushort4 hv[8];
#pragma unroll
        for (int i = 0; i < 8; ++i) {
            const unsigned off32 = ((pk[i] & 0xffffu) << 6) + chb;  // cell*64B
            hv[i] = *(const ushort4*)(vb + off32);
        }

        float4 acc = {0.f, 0.f, 0.f, 0.f};
#pragma unroll
        for (int i = 0; i < 8; ++i) {
            const float wt = h2f((unsigned short)(pk[i] >> 16));
            acc.x = fmaf(h2f(hv[i].x), wt, acc.x);
            acc.y = fmaf(h2f(hv[i].y), wt, acc.y);
            acc.z = fmaf(h2f(hv[i].z), wt, acc.z);
            acc.w = fmaf(h2f(hv[i].w), wt, acc.w);
        }
        // reduce over cg: xor8 = DPP row_ror:8, xor16/xor32 = permlane swaps
        acc.x += dpp_mov_f32<0x128>(acc.x);
        acc.y += dpp_mov_f32<0x128>(acc.y);
        acc.z += dpp_mov_f32<0x128>(acc.z);
        acc.w += dpp_mov_f32<0x128>(acc.w);
        acc.x = bfly_add16(acc.x);  acc.y = bfly_add16(acc.y);
        acc.z = bfly_add16(acc.z);  acc.w = bfly_add16(acc.w);
        acc.x = bfly_add32(acc.x);  acc.y = bfly_add32(acc.y);
        acc.z = bfly_add32(acc.z);  acc.w = bfly_add32(acc.w);

        if (lane < 8) {
            ushort4 hz;
            hz.x = f2h(acc.x); hz.y = f2h(acc.y);
            hz.z = f2h(acc.z); hz.w = f2h(acc.w);
            *(ushort4*)(out2 + (size_t)q2 * 256 + m * 32 + lane * 4) = hz;
        }
    }
}

// ---------------------------------------------------------------------------
// gemm_out_k: out = out2 @ W_out + b_out; A and Bt fp16, single f16 MFMA.
// 64x64 tile / 256 threads, wave = 32x32 quadrant; grid (312, 4) = 1248
// blocks (4.9/CU).
// ---------------------------------------------------------------------------
__global__ __launch_bounds__(256) void gemm_out_k(
    const unsigned short* __restrict__ A, const unsigned short* __restrict__ Bt,
    const float* __restrict__ bias, float* __restrict__ C, int Q)
{
    __shared__ unsigned short As[64][72];
    __shared__ unsigned short Bs[64][72];

    const int t = threadIdx.x;
    const int w = t >> 6, lane = t & 63;
    const int lr = lane & 15, quad = lane >> 4;
    const int rwl = (w & 1) * 32, cwl = (w >> 1) * 32;
    const int r0 = blockIdx.x * 64, c0 = blockIdx.y * 64;

    const int a_r = t >> 2, a_k = (t & 3) * 16;

    int ar = r0 + a_r; if (ar >= Q) ar = Q - 1;
    const unsigned short* Arow = A + (size_t)ar * 256;
    const unsigned short* Brow = Bt + (size_t)(c0 + a_r) * 256;

    f32x4 acc[2][2];
#pragma unroll
    for (int i = 0; i < 2; ++i)
#pragma unroll
        for (int j = 0; j < 2; ++j) acc[i][j] = (f32x4){0.f, 0.f, 0.f, 0.f};

    u16x8 av[2], bv[2];
    auto load_chunk = [&](int kc) {
#pragma unroll
        for (int j = 0; j < 2; ++j) {
            av[j] = *(const u16x8*)(Arow + kc + a_k + j * 8);
            bv[j] = *(const u16x8*)(Brow + kc + a_k + j * 8);
        }
    };
    auto stage_store = [&]() {
#pragma unroll
        for (int j = 0; j < 2; ++j) {
            *(u16x8*)&As[a_r][a_k + j * 8] = av[j];
            *(u16x8*)&Bs[a_r][a_k + j * 8] = bv[j];
        }
    };

    load_chunk(0);
    stage_store();
    __syncthreads();

#pragma unroll
    for (int ch = 0; ch < 4; ++ch) {
        if (ch < 3) load_chunk((ch + 1) * 64);
#pragma unroll
        for (int ks = 0; ks < 2; ++ks) {
            const int kb = ks * 32 + quad * 8;
            f16x8 af[2], bfr[2];
#pragma unroll
            for (int rt = 0; rt < 2; ++rt)
                af[rt] = *(const f16x8*)&As[rwl + rt * 16 + lr][kb];
#pragma unroll
            for (int ct = 0; ct < 2; ++ct)
                bfr[ct] = *(const f16x8*)&Bs[cwl + ct * 16 + lr][kb];
#pragma unroll
            for (int rt = 0; rt < 2; ++rt)
#pragma unroll
                for (int ct = 0; ct < 2; ++ct)
                    acc[rt][ct] = __builtin_amdgcn_mfma_f32_16x16x32_f16(
                        af[rt], bfr[ct], acc[rt][ct], 0, 0, 0);
        }
        if (ch < 3) { __syncthreads(); stage_store(); __syncthreads(); }
    }

#pragma unroll
    for (int ct = 0; ct < 2; ++ct) {
        const int col = c0 + cwl + ct * 16 + lr;
        const float bb = bias[col];
#pragma unroll
        for (int rt = 0; rt < 2; ++rt)
#pragma unroll
            for (int reg = 0; reg < 4; ++reg) {
                const int r = r0 + rwl + rt * 16 + quad * 4 + reg;
                if (r < Q) C[(size_t)r * 256 + col] = acc[rt][ct][reg] + bb;
            }
    }
}

// ---------------------------------------------------------------------------
extern "C" void kernel_launch(void* const* d_in, const int* in_sizes, int n_in,
                              void* d_out, int out_size, void* d_ws, size_t ws_size,
                              hipStream_t stream)
{
    const float* query = (const float*)d_in[0];                 // (Q, 256)
    const float* refpt = (const float*)d_in[1];                 // (Q, 4, 2)
    const float* inflat = (const float*)d_in[2];                // (Q, 256)
    const unsigned char* mask = (const unsigned char*)d_in[3];  // (Q,)
    const float* W_off = (const float*)d_in[4];                 // (256, 256)
    const float* b_off = (const float*)d_in[5];                 // (256,)
    const float* W_attn = (const float*)d_in[6];                // (256, 128)
    const float* b_attn = (const float*)d_in[7];                // (128,)
    const float* W_val = (const float*)d_in[8];                 // (256, 256)
    const float* b_val = (const float*)d_in[9];                 // (256,)
    const float* W_out = (const float*)d_in[10];                // (256, 256)
    const float* b_out = (const float*)d_in[11];                // (256,)
    float* out = (float*)d_out;

    const int Q = in_sizes[0] / DMODEL;  // 19947
    const int QD = Q * DMODEL;

    // Workspace layout (all chunks keep 8B alignment)
    unsigned short* value_h  = (unsigned short*)d_ws;                     // Q*256, m-major
    float*          offo     = (float*)(value_h + (size_t)QD);            // Q*256
    unsigned short* logits_h = (unsigned short*)(offo + (size_t)QD);      // Q*128
    unsigned short* out2     = logits_h + (size_t)Q * 128;                // Q*256
    unsigned short* inflat_h = out2 + (size_t)QD;
    unsigned short* query_h  = inflat_h + (size_t)QD;
    unsigned short* WtVal    = query_h + (size_t)QD;
    unsigned short* WtOff    = WtVal  + 65536;
    unsigned short* WtAttn   = WtOff  + 65536;   // 128*256
    unsigned short* WtOut    = WtAttn + 32768;

    const int rb = (Q + 63) / 64;                      // 312
    const int na = (2 * QD + 2047) / 2048;             // A-convert blocks
    const int nqb = (Q + 15) / 16;                     // msda q-blocks (16 q each)

    // 1) weight transposes + A fp16 conversion, one dispatch
    prep_k<<<56 + na, 256, 0, stream>>>(W_val, W_off, W_attn, W_out,
                                        WtVal, WtOff, WtAttn, WtOut,
                                        inflat, query, inflat_h, query_h, QD);
    // 2) value(fp16 m-major) / off(f32) / logits(fp16, *log2e) GEMMs
    gemm_in_k<<<dim3(rb, 5), 256, 0, stream>>>(
        inflat_h, query_h, WtVal, WtOff, WtAttn, b_val, b_off, b_attn,
        value_h, offo, logits_h, Q, mask);
    // 3) fused softmax + sample + accumulate -> out2 (fp16); m = blockIdx&7
    msda_k<<<nqb * 8, 256, 0, stream>>>(value_h, offo, logits_h, refpt,
                                        out2, Q);
    // 4) out = out2 @ W_out + b_out (single f16 MFMA path, 64x64 tiles)
    gemm_out_k<<<dim3(rb, 4), 256, 0, stream>>>(out2, WtOut, b_out, out, Q);
}